// Round 9
// baseline (1588.527 us; speedup 1.0000x reference)
//
#include <hip/hip_runtime.h>
#include <hip/hip_bf16.h>
#include <math.h>

#define NN 100000
#define EE 3200000
#define FIN 512
#define HID 256
#define CLS 64
#define KST 20
#define NBUK 98        // dst-range buckets (1024 nodes each)
#define BCAP 36864     // bucket capacity (mean 32653, far tail-safe; input fixed)

typedef __attribute__((ext_vector_type(8))) short bf16x8;
typedef __attribute__((ext_vector_type(4))) float f32x4;
typedef __attribute__((ext_vector_type(4))) unsigned u32x4;   // native vec: ok for nontemporal builtins

__device__ __forceinline__ short f2bf(float f) {
    union { __hip_bfloat16 b; short s; } u;
    u.b = __float2bfloat16(f);
    return u.s;
}
__device__ __forceinline__ float bf2f(__hip_bfloat16 b) { return __bfloat162float(b); }
__device__ __forceinline__ float lobf(unsigned u) { return __uint_as_float(u << 16); }
__device__ __forceinline__ float hibf(unsigned u) { return __uint_as_float(u & 0xffff0000u); }
__device__ __forceinline__ unsigned packbf(float lo, float hi) {
    return (unsigned)(unsigned short)f2bf(lo) | ((unsigned)(unsigned short)f2bf(hi) << 16);
}

// ---------------- bucketed CSR build ----------------

__global__ void zerocur_kernel(int* __restrict__ gcur) {
    if (threadIdx.x < NBUK) gcur[threadIdx.x] = 0;
}

__global__ __launch_bounds__(256) void bucket_kernel(const int* __restrict__ esrc,
                                                     const int* __restrict__ edst,
                                                     unsigned* __restrict__ gbuf,
                                                     int* __restrict__ gcur) {
    __shared__ int lcnt[NBUK];
    __shared__ int lbase[NBUK];
    const int t = threadIdx.x;
    for (int i = t; i < NBUK; i += 256) lcnt[i] = 0;
    __syncthreads();

    const int e0 = blockIdx.x * 2048;
    int bkt[8], rnk[8];
    unsigned rec[8];
#pragma unroll
    for (int i = 0; i < 8; ++i) {
        int idx = e0 + i * 256 + t;
        if (idx < EE) {
            int d = edst[idx];
            int s = esrc[idx];
            bkt[i] = d >> 10;
            rec[i] = ((unsigned)(d & 1023) << 17) | (unsigned)s;
            rnk[i] = atomicAdd(&lcnt[bkt[i]], 1);
        } else {
            bkt[i] = -1;
        }
    }
    __syncthreads();
    for (int i = t; i < NBUK; i += 256) lbase[i] = atomicAdd(&gcur[i], lcnt[i]);
    __syncthreads();
#pragma unroll
    for (int i = 0; i < 8; ++i)
        if (bkt[i] >= 0)
            gbuf[(size_t)bkt[i] * BCAP + lbase[bkt[i]] + rnk[i]] = rec[i];
}

// per-bucket: prefix over gcur (in-block), hist -> scan -> rowptr/dis, place csrc
__global__ __launch_bounds__(256) void csr_kernel(const unsigned* __restrict__ gbuf,
                                                  const int* __restrict__ gcur,
                                                  int* __restrict__ rowptr,
                                                  float* __restrict__ dis,
                                                  int* __restrict__ csrc) {
    __shared__ int hist[1024];
    __shared__ int part[256];
    __shared__ int rp[1024];
    __shared__ int gc[NBUK];
    const int b = blockIdx.x;
    const int t = threadIdx.x;
    const int d0 = b << 10;
    const unsigned* rbuf = gbuf + (size_t)b * BCAP;

    if (t < NBUK) gc[t] = gcur[t];
#pragma unroll
    for (int i = 0; i < 4; ++i) hist[t * 4 + i] = 0;
    __syncthreads();

    int base = 0;
    for (int i = 0; i < b; ++i) base += gc[i];     // LDS broadcast, uniform
    const int nrec = gc[b];

    for (int r = t; r < nrec; r += 256)
        atomicAdd(&hist[rbuf[r] >> 17], 1);
    __syncthreads();

    int h[4], sum4 = 0;
#pragma unroll
    for (int i = 0; i < 4; ++i) { h[i] = hist[t * 4 + i]; sum4 += h[i]; }
    part[t] = sum4;
    __syncthreads();
    for (int off = 1; off < 256; off <<= 1) {
        int v = (t >= off) ? part[t - off] : 0;
        __syncthreads();
        part[t] += v;
        __syncthreads();
    }

    int run = base + part[t] - sum4;
#pragma unroll
    for (int i = 0; i < 4; ++i) {
        int d = d0 + t * 4 + i;
        if (d < NN) {
            rowptr[d] = run;
            rp[t * 4 + i] = run;
            dis[d] = rsqrtf((float)(h[i] + 1));
        }
        run += h[i];
    }
    if (b == 0 && t == 0) rowptr[NN] = EE;
#pragma unroll
    for (int i = 0; i < 4; ++i) hist[t * 4 + i] = 0;
    __syncthreads();

    for (int r = t; r < nrec; r += 256) {
        unsigned rec = rbuf[r];
        int dloc = rec >> 17;
        int pos = atomicAdd(&hist[dloc], 1);
        csrc[rp[dloc] + pos] = (int)(rec & 0x1FFFFu);
    }
}

// ---------------- weight prep: fragment-tiled bf16 ----------------

__global__ void w1t_kernel(const float* __restrict__ W1, __hip_bfloat16* __restrict__ W1Tt) {
    const int c = threadIdx.x;       // 0..255
    const int kg = blockIdx.x;       // 0..63
    bf16x8 o;
#pragma unroll
    for (int j = 0; j < 8; ++j) o[j] = f2bf(W1[(size_t)(kg * 8 + j) * HID + c]);
    size_t dst = ((size_t)((c >> 4) * 16 + (kg >> 2))) * 512 + (c & 15) * 32 + (kg & 3) * 8;
    *(bf16x8*)((short*)W1Tt + dst) = o;
}

__global__ void w2t_kernel(const float* __restrict__ W2, __hip_bfloat16* __restrict__ W2Tt) {
    const int c = threadIdx.x;       // 0..63
    const int kg = blockIdx.x;       // 0..31
    bf16x8 o;
#pragma unroll
    for (int j = 0; j < 8; ++j) o[j] = f2bf(W2[(size_t)(kg * 8 + j) * CLS + c]);
    size_t dst = ((size_t)((c >> 4) * 8 + (kg >> 2))) * 512 + (c & 15) * 32 + (kg & 3) * 8;
    *(bf16x8*)((short*)W2Tt + dst) = o;
}

// ---------------- MFMA MLP: 64-k chunks, 2-deep register prefetch ----------------
__global__ __launch_bounds__(256, 3) void mlp_kernel(const float* __restrict__ x,
                                                     const __hip_bfloat16* __restrict__ W1Tt,
                                                     const float* __restrict__ b1,
                                                     const __hip_bfloat16* __restrict__ W2Tt,
                                                     const float* __restrict__ b2,
                                                     const float* __restrict__ dis,
                                                     __hip_bfloat16* __restrict__ hb,
                                                     __hip_bfloat16* __restrict__ y0) {
    __shared__ __align__(16) char Alds[64 * 128];   // 64 rows x 64 k bf16, swizzled (8 KB)
    __shared__ __align__(16) char Tlds[64 * 512];   // 64 rows x 256 cols bf16, swizzled (32 KB)

    const int t = threadIdx.x;
    const int w = t >> 6;
    const int lane = t & 63;
    const int lg = lane >> 4;
    const int li = lane & 15;
    const int loff = li * 32 + lg * 8;
    const int r0 = blockIdx.x * 64;

    const short* W1s = (const short*)W1Tt;
    const short* W2s = (const short*)W2Tt;

    // staging map: 4 float4 per thread per 64-k chunk (1024 float4 total)
    const float* xp[4];
    int srow[4], sc4[4];
#pragma unroll
    for (int i = 0; i < 4; ++i) {
        int f = t + i * 256;
        srow[i] = f >> 4;              // 16 float4 per row
        sc4[i] = (f & 15) << 2;
        int sr = r0 + srow[i]; if (sr >= NN) sr = NN - 1;
        xp[i] = x + (size_t)sr * FIN + sc4[i];
    }

    float4 av0[4], av1[4];
#pragma unroll
    for (int i = 0; i < 4; ++i) av0[i] = *(const float4*)(xp[i]);            // chunk 0
#pragma unroll
    for (int i = 0; i < 4; ++i) av1[i] = *(const float4*)(xp[i] + 64);       // chunk 1

    f32x4 acc1[4][4];
#pragma unroll
    for (int mf = 0; mf < 4; ++mf)
#pragma unroll
        for (int nf = 0; nf < 4; ++nf)
#pragma unroll
            for (int r = 0; r < 4; ++r) acc1[mf][nf][r] = 0.f;

#define MLP_STEP(CUR, KC)                                                            \
    {                                                                                \
        _Pragma("unroll")                                                            \
        for (int i = 0; i < 4; ++i) {                                                \
            short4 bq;                                                               \
            bq.x = f2bf(CUR[i].x); bq.y = f2bf(CUR[i].y);                            \
            bq.z = f2bf(CUR[i].z); bq.w = f2bf(CUR[i].w);                            \
            int byte = srow[i] * 128 + ((sc4[i] * 2) ^ ((srow[i] & 7) << 4));        \
            *(short4*)(Alds + byte) = bq;                                            \
        }                                                                            \
        asm volatile("s_waitcnt lgkmcnt(0)" ::: "memory");                           \
        __builtin_amdgcn_s_barrier();                                                \
        asm volatile("" ::: "memory");                                               \
        if ((KC) + 2 < 8) {                                                          \
            _Pragma("unroll")                                                        \
            for (int i = 0; i < 4; ++i)                                              \
                CUR[i] = *(const float4*)(xp[i] + ((KC) + 2) * 64);                  \
        }                                                                            \
        _Pragma("unroll")                                                            \
        for (int ks = 0; ks < 2; ++ks) {                                             \
            bf16x8 af[4], bfw[4];                                                    \
            _Pragma("unroll")                                                        \
            for (int mf = 0; mf < 4; ++mf) {                                         \
                int row = mf * 16 + li;                                              \
                int kb = ks * 64 + lg * 16;                                          \
                af[mf] = *(const bf16x8*)(Alds + row * 128 + (kb ^ ((row & 7) << 4))); \
            }                                                                        \
            _Pragma("unroll")                                                        \
            for (int nf = 0; nf < 4; ++nf)                                           \
                bfw[nf] = *(const bf16x8*)(W1s +                                     \
                    ((size_t)((w * 4 + nf) * 16 + (KC) * 2 + ks)) * 512 + loff);     \
            _Pragma("unroll")                                                        \
            for (int mf = 0; mf < 4; ++mf)                                           \
                _Pragma("unroll")                                                    \
                for (int nf = 0; nf < 4; ++nf)                                       \
                    acc1[mf][nf] = __builtin_amdgcn_mfma_f32_16x16x32_bf16(          \
                        af[mf], bfw[nf], acc1[mf][nf], 0, 0, 0);                     \
        }                                                                            \
        asm volatile("" ::: "memory");                                               \
        __builtin_amdgcn_s_barrier();                                                \
        asm volatile("" ::: "memory");                                               \
    }

#pragma unroll
    for (int kc = 0; kc < 8; kc += 2) {
        MLP_STEP(av0, kc);
        MLP_STEP(av1, kc + 1);
    }
#undef MLP_STEP

    // T = relu(acc1 + b1) -> swizzled LDS (wave w owns cols w*64..w*64+63)
#pragma unroll
    for (int nf = 0; nf < 4; ++nf) {
        const float bv = b1[w * 64 + nf * 16 + li];
        const int col = w * 64 + nf * 16 + li;
#pragma unroll
        for (int mf = 0; mf < 4; ++mf) {
#pragma unroll
            for (int r = 0; r < 4; ++r) {
                int row = mf * 16 + lg * 4 + r;
                float tv = fmaxf(acc1[mf][nf][r] + bv, 0.f);
                int byte = row * 512 + ((col * 2) ^ ((row & 7) << 4));
                *(short*)(Tlds + byte) = f2bf(tv);
            }
        }
    }
    __syncthreads();

    // GEMM2: wave w -> rows [w*16, w*16+16), K = 256
    f32x4 acc2[4];
#pragma unroll
    for (int nf = 0; nf < 4; ++nf)
#pragma unroll
        for (int r = 0; r < 4; ++r) acc2[nf][r] = 0.f;

#pragma unroll
    for (int kt2 = 0; kt2 < 8; ++kt2) {
        int row = w * 16 + li;
        int kb = (kt2 * 32 + lg * 8) * 2;
        bf16x8 at = *(const bf16x8*)(Tlds + row * 512 + (kb ^ ((row & 7) << 4)));
#pragma unroll
        for (int nf = 0; nf < 4; ++nf) {
            bf16x8 bw = *(const bf16x8*)(W2s + ((size_t)(nf * 8 + kt2)) * 512 + loff);
            acc2[nf] = __builtin_amdgcn_mfma_f32_16x16x32_bf16(at, bw, acc2[nf], 0, 0, 0);
        }
    }

#pragma unroll
    for (int r = 0; r < 4; ++r) {
        int row = r0 + w * 16 + lg * 4 + r;
        if (row < NN) {
            const float dv = dis[row];
#pragma unroll
            for (int nf = 0; nf < 4; ++nf) {
                float hv = acc2[nf][r] + b2[nf * 16 + li];
                size_t o = (size_t)row * CLS + nf * 16 + li;
                hb[o] = __float2bfloat16(hv);
                y0[o] = __float2bfloat16(hv * dv);
            }
        }
    }
}

// ---------------- propagation: 8 lanes/edge, nt-hinted streams ----------------

__device__ __forceinline__ void acc8(float* a, u32x4 d) {
    a[0] += lobf(d.x); a[1] += hibf(d.x);
    a[2] += lobf(d.y); a[3] += hibf(d.y);
    a[4] += lobf(d.z); a[5] += hibf(d.z);
    a[6] += lobf(d.w); a[7] += hibf(d.w);
}

template <int LAST>
__global__ __launch_bounds__(256) void prop_kernel(const __hip_bfloat16* __restrict__ yin,
                                                   const __hip_bfloat16* __restrict__ hb,
                                                   const float* __restrict__ dis,
                                                   const int* __restrict__ rowptr,
                                                   const int* __restrict__ csrc,
                                                   __hip_bfloat16* __restrict__ yout,
                                                   float* __restrict__ zout) {
    const int node = blockIdx.x * 4 + (threadIdx.x >> 6);
    const int lane = threadIdx.x & 63;
    const int g = lane >> 3;
    const int ci = lane & 7;

    const u32x4* Y = (const u32x4*)yin;

    int p = __builtin_amdgcn_readfirstlane(rowptr[node]);
    const int e = __builtin_amdgcn_readfirstlane(rowptr[node + 1]);

    float a[8];
#pragma unroll
    for (int j = 0; j < 8; ++j) a[j] = 0.f;

    for (; p + 32 <= e; p += 32) {
        int s0 = __builtin_nontemporal_load(csrc + p + g);
        int s1 = __builtin_nontemporal_load(csrc + p + 8 + g);
        int s2 = __builtin_nontemporal_load(csrc + p + 16 + g);
        int s3 = __builtin_nontemporal_load(csrc + p + 24 + g);
        u32x4 d0 = Y[(size_t)s0 * 8 + ci];
        u32x4 d1 = Y[(size_t)s1 * 8 + ci];
        u32x4 d2 = Y[(size_t)s2 * 8 + ci];
        u32x4 d3 = Y[(size_t)s3 * 8 + ci];
        acc8(a, d0); acc8(a, d1); acc8(a, d2); acc8(a, d3);
    }
    for (; p + 8 <= e; p += 8) {
        int s = __builtin_nontemporal_load(csrc + p + g);
        u32x4 d = Y[(size_t)s * 8 + ci];
        acc8(a, d);
    }
    if (p < e) {
        int q = p + g;
        int s = __builtin_nontemporal_load(csrc + ((q < e) ? q : (e - 1)));
        u32x4 d = Y[(size_t)s * 8 + ci];
        if (q < e) acc8(a, d);
    }

#pragma unroll
    for (int j = 0; j < 8; ++j) {
        a[j] += __shfl_xor(a[j], 8);
        a[j] += __shfl_xor(a[j], 16);
        a[j] += __shfl_xor(a[j], 32);
    }

    const float din = dis[node];
    u32x4 dself = Y[(size_t)node * 8 + ci];
    u32x4 dh = __builtin_nontemporal_load((const u32x4*)hb + (size_t)node * 8 + ci);
    float hv[8], z[8];
    acc8(a, dself);
    hv[0] = lobf(dh.x); hv[1] = hibf(dh.x);
    hv[2] = lobf(dh.y); hv[3] = hibf(dh.y);
    hv[4] = lobf(dh.z); hv[5] = hibf(dh.z);
    hv[6] = lobf(dh.w); hv[7] = hibf(dh.w);
#pragma unroll
    for (int j = 0; j < 8; ++j) z[j] = 0.9f * din * a[j] + 0.1f * hv[j];

    if (LAST) {
        float m = z[0];
#pragma unroll
        for (int j = 1; j < 8; ++j) m = fmaxf(m, z[j]);
        m = fmaxf(m, __shfl_xor(m, 1));
        m = fmaxf(m, __shfl_xor(m, 2));
        m = fmaxf(m, __shfl_xor(m, 4));
        float ss = 0.f;
#pragma unroll
        for (int j = 0; j < 8; ++j) ss += __expf(z[j] - m);
        ss += __shfl_xor(ss, 1);
        ss += __shfl_xor(ss, 2);
        ss += __shfl_xor(ss, 4);
        const float lgv = __logf(ss);
        if (g == 0) {
            f32x4 o0, o1;
            o0[0] = z[0] - m - lgv; o0[1] = z[1] - m - lgv; o0[2] = z[2] - m - lgv; o0[3] = z[3] - m - lgv;
            o1[0] = z[4] - m - lgv; o1[1] = z[5] - m - lgv; o1[2] = z[6] - m - lgv; o1[3] = z[7] - m - lgv;
            ((f32x4*)zout)[(size_t)node * 16 + ci * 2] = o0;
            ((f32x4*)zout)[(size_t)node * 16 + ci * 2 + 1] = o1;
        }
    } else {
        if (g == 0) {
            u32x4 o;
            o.x = packbf(z[0] * din, z[1] * din);
            o.y = packbf(z[2] * din, z[3] * din);
            o.z = packbf(z[4] * din, z[5] * din);
            o.w = packbf(z[6] * din, z[7] * din);
            ((u32x4*)yout)[(size_t)node * 8 + ci] = o;
        }
    }
}

extern "C" void kernel_launch(void* const* d_in, const int* in_sizes, int n_in,
                              void* d_out, int out_size, void* d_ws, size_t ws_size,
                              hipStream_t stream) {
    const float* x  = (const float*)d_in[0];
    const int*   ei = (const int*)d_in[1];
    const float* W1 = (const float*)d_in[2];
    const float* b1 = (const float*)d_in[3];
    const float* W2 = (const float*)d_in[4];
    const float* b2 = (const float*)d_in[5];
    float* out = (float*)d_out;

    const int* esrc = ei;
    const int* edst = ei + EE;

    char* w = (char*)d_ws;
    auto alloc = [&](size_t bytes) {
        char* p = w;
        w += (bytes + 255) & ~(size_t)255;
        return p;
    };
    __hip_bfloat16* hb   = (__hip_bfloat16*)alloc((size_t)NN * CLS * 2);
    __hip_bfloat16* yA   = (__hip_bfloat16*)alloc((size_t)NN * CLS * 2);
    __hip_bfloat16* yB   = (__hip_bfloat16*)alloc((size_t)NN * CLS * 2);
    __hip_bfloat16* W1Tt = (__hip_bfloat16*)alloc((size_t)HID * FIN * 2);
    __hip_bfloat16* W2Tt = (__hip_bfloat16*)alloc((size_t)CLS * HID * 2);
    float* dis    = (float*)alloc((size_t)NN * 4);
    int* rowptr   = (int*)alloc((size_t)(NN + 1) * 4);
    int* csrc     = (int*)alloc((size_t)EE * 4);
    unsigned* gbuf = (unsigned*)alloc((size_t)NBUK * BCAP * 4);
    int* gcur     = (int*)alloc(NBUK * 4);

    // CSR build (bucketed, L2-local scatter)
    zerocur_kernel<<<1, 128, 0, stream>>>(gcur);
    bucket_kernel<<<(EE + 2047) / 2048, 256, 0, stream>>>(esrc, edst, gbuf, gcur);
    csr_kernel<<<NBUK, 256, 0, stream>>>(gbuf, gcur, rowptr, dis, csrc);

    // weight prep + MLP
    w1t_kernel<<<FIN / 8, HID, 0, stream>>>(W1, W1Tt);
    w2t_kernel<<<HID / 8, CLS, 0, stream>>>(W2, W2Tt);
    mlp_kernel<<<(NN + 63) / 64, 256, 0, stream>>>(x, W1Tt, b1, W2Tt, b2, dis, hb, yA);

    // propagation
    const __hip_bfloat16* yin = yA;
    __hip_bfloat16* yout = yB;
    for (int s = 0; s < KST - 1; ++s) {
        prop_kernel<0><<<NN / 4, 256, 0, stream>>>(yin, hb, dis, rowptr, csrc, yout, nullptr);
        const __hip_bfloat16* t2 = yin;
        yin = yout;
        yout = (__hip_bfloat16*)t2;
    }
    prop_kernel<1><<<NN / 4, 256, 0, stream>>>(yin, hb, dis, rowptr, csrc, nullptr, out);
}

// Round 10
// 1362.858 us; speedup vs baseline: 1.1656x; 1.1656x over previous
//
#include <hip/hip_runtime.h>
#include <hip/hip_bf16.h>
#include <math.h>

#define NN 100000
#define EE 3200000
#define FIN 512
#define HID 256
#define CLS 64
#define KST 20
#define NBUK 98        // dst-range buckets (1024 nodes each)
#define BCAP 36864     // bucket capacity (mean 32653, far tail-safe; input fixed)

typedef __attribute__((ext_vector_type(8))) short bf16x8;
typedef __attribute__((ext_vector_type(4))) float f32x4;
typedef __attribute__((ext_vector_type(4))) unsigned u32x4;

__device__ __forceinline__ short f2bf(float f) {
    union { __hip_bfloat16 b; short s; } u;
    u.b = __float2bfloat16(f);
    return u.s;
}
__device__ __forceinline__ float bf2f(__hip_bfloat16 b) { return __bfloat162float(b); }
__device__ __forceinline__ float lobf(unsigned u) { return __uint_as_float(u << 16); }
__device__ __forceinline__ float hibf(unsigned u) { return __uint_as_float(u & 0xffff0000u); }
__device__ __forceinline__ unsigned packbf(float lo, float hi) {
    return (unsigned)(unsigned short)f2bf(lo) | ((unsigned)(unsigned short)f2bf(hi) << 16);
}

// ---------------- bucketed CSR build ----------------

__global__ void zerocur_kernel(int* __restrict__ gcur) {
    if (threadIdx.x < NBUK) gcur[threadIdx.x] = 0;
}

__global__ __launch_bounds__(256) void bucket_kernel(const int* __restrict__ esrc,
                                                     const int* __restrict__ edst,
                                                     unsigned* __restrict__ gbuf,
                                                     int* __restrict__ gcur) {
    __shared__ int lcnt[NBUK];
    __shared__ int lbase[NBUK];
    const int t = threadIdx.x;
    for (int i = t; i < NBUK; i += 256) lcnt[i] = 0;
    __syncthreads();

    const int e0 = blockIdx.x * 2048;
    int bkt[8], rnk[8];
    unsigned rec[8];
#pragma unroll
    for (int i = 0; i < 8; ++i) {
        int idx = e0 + i * 256 + t;
        if (idx < EE) {
            int d = edst[idx];
            int s = esrc[idx];
            bkt[i] = d >> 10;
            rec[i] = ((unsigned)(d & 1023) << 17) | (unsigned)s;
            rnk[i] = atomicAdd(&lcnt[bkt[i]], 1);
        } else {
            bkt[i] = -1;
        }
    }
    __syncthreads();
    for (int i = t; i < NBUK; i += 256) lbase[i] = atomicAdd(&gcur[i], lcnt[i]);
    __syncthreads();
#pragma unroll
    for (int i = 0; i < 8; ++i)
        if (bkt[i] >= 0)
            gbuf[(size_t)bkt[i] * BCAP + lbase[bkt[i]] + rnk[i]] = rec[i];
}

// per-bucket: prefix over gcur (in-block), hist -> scan -> rowptr/dis, place csrc
__global__ __launch_bounds__(256) void csr_kernel(const unsigned* __restrict__ gbuf,
                                                  const int* __restrict__ gcur,
                                                  int* __restrict__ rowptr,
                                                  float* __restrict__ dis,
                                                  int* __restrict__ csrc) {
    __shared__ int hist[1024];
    __shared__ int part[256];
    __shared__ int rp[1024];
    __shared__ int gc[NBUK];
    const int b = blockIdx.x;
    const int t = threadIdx.x;
    const int d0 = b << 10;
    const unsigned* rbuf = gbuf + (size_t)b * BCAP;

    if (t < NBUK) gc[t] = gcur[t];
#pragma unroll
    for (int i = 0; i < 4; ++i) hist[t * 4 + i] = 0;
    __syncthreads();

    int base = 0;
    for (int i = 0; i < b; ++i) base += gc[i];
    const int nrec = gc[b];

    for (int r = t; r < nrec; r += 256)
        atomicAdd(&hist[rbuf[r] >> 17], 1);
    __syncthreads();

    int h[4], sum4 = 0;
#pragma unroll
    for (int i = 0; i < 4; ++i) { h[i] = hist[t * 4 + i]; sum4 += h[i]; }
    part[t] = sum4;
    __syncthreads();
    for (int off = 1; off < 256; off <<= 1) {
        int v = (t >= off) ? part[t - off] : 0;
        __syncthreads();
        part[t] += v;
        __syncthreads();
    }

    int run = base + part[t] - sum4;
#pragma unroll
    for (int i = 0; i < 4; ++i) {
        int d = d0 + t * 4 + i;
        if (d < NN) {
            rowptr[d] = run;
            rp[t * 4 + i] = run;
            dis[d] = rsqrtf((float)(h[i] + 1));
        }
        run += h[i];
    }
    if (b == 0 && t == 0) rowptr[NN] = EE;
#pragma unroll
    for (int i = 0; i < 4; ++i) hist[t * 4 + i] = 0;
    __syncthreads();

    for (int r = t; r < nrec; r += 256) {
        unsigned rec = rbuf[r];
        int dloc = rec >> 17;
        int pos = atomicAdd(&hist[dloc], 1);
        csrc[rp[dloc] + pos] = (int)(rec & 0x1FFFFu);
    }
}

// ---------------- weight prep: fragment-tiled bf16 ----------------

__global__ void w1t_kernel(const float* __restrict__ W1, __hip_bfloat16* __restrict__ W1Tt) {
    const int c = threadIdx.x;       // 0..255
    const int kg = blockIdx.x;       // 0..63
    bf16x8 o;
#pragma unroll
    for (int j = 0; j < 8; ++j) o[j] = f2bf(W1[(size_t)(kg * 8 + j) * HID + c]);
    size_t dst = ((size_t)((c >> 4) * 16 + (kg >> 2))) * 512 + (c & 15) * 32 + (kg & 3) * 8;
    *(bf16x8*)((short*)W1Tt + dst) = o;
}

__global__ void w2t_kernel(const float* __restrict__ W2, __hip_bfloat16* __restrict__ W2Tt) {
    const int c = threadIdx.x;       // 0..63
    const int kg = blockIdx.x;       // 0..31
    bf16x8 o;
#pragma unroll
    for (int j = 0; j < 8; ++j) o[j] = f2bf(W2[(size_t)(kg * 8 + j) * CLS + c]);
    size_t dst = ((size_t)((c >> 4) * 8 + (kg >> 2))) * 512 + (c & 15) * 32 + (kg & 3) * 8;
    *(bf16x8*)((short*)W2Tt + dst) = o;
}

// ---------------- MFMA MLP: 64-k chunks, 2-deep register prefetch ----------------
__global__ __launch_bounds__(256, 3) void mlp_kernel(const float* __restrict__ x,
                                                     const __hip_bfloat16* __restrict__ W1Tt,
                                                     const float* __restrict__ b1,
                                                     const __hip_bfloat16* __restrict__ W2Tt,
                                                     const float* __restrict__ b2,
                                                     const float* __restrict__ dis,
                                                     __hip_bfloat16* __restrict__ hb,
                                                     __hip_bfloat16* __restrict__ y0) {
    __shared__ __align__(16) char Alds[64 * 128];   // 64 rows x 64 k bf16, swizzled (8 KB)
    __shared__ __align__(16) char Tlds[64 * 512];   // 64 rows x 256 cols bf16, swizzled (32 KB)

    const int t = threadIdx.x;
    const int w = t >> 6;
    const int lane = t & 63;
    const int lg = lane >> 4;
    const int li = lane & 15;
    const int loff = li * 32 + lg * 8;
    const int r0 = blockIdx.x * 64;

    const short* W1s = (const short*)W1Tt;
    const short* W2s = (const short*)W2Tt;

    const float* xp[4];
    int srow[4], sc4[4];
#pragma unroll
    for (int i = 0; i < 4; ++i) {
        int f = t + i * 256;
        srow[i] = f >> 4;              // 16 float4 per row
        sc4[i] = (f & 15) << 2;
        int sr = r0 + srow[i]; if (sr >= NN) sr = NN - 1;
        xp[i] = x + (size_t)sr * FIN + sc4[i];
    }

    float4 av0[4], av1[4];
#pragma unroll
    for (int i = 0; i < 4; ++i) av0[i] = *(const float4*)(xp[i]);            // chunk 0
#pragma unroll
    for (int i = 0; i < 4; ++i) av1[i] = *(const float4*)(xp[i] + 64);       // chunk 1

    f32x4 acc1[4][4];
#pragma unroll
    for (int mf = 0; mf < 4; ++mf)
#pragma unroll
        for (int nf = 0; nf < 4; ++nf)
#pragma unroll
            for (int r = 0; r < 4; ++r) acc1[mf][nf][r] = 0.f;

#define MLP_STEP(CUR, KC)                                                            \
    {                                                                                \
        _Pragma("unroll")                                                            \
        for (int i = 0; i < 4; ++i) {                                                \
            short4 bq;                                                               \
            bq.x = f2bf(CUR[i].x); bq.y = f2bf(CUR[i].y);                            \
            bq.z = f2bf(CUR[i].z); bq.w = f2bf(CUR[i].w);                            \
            int byte = srow[i] * 128 + ((sc4[i] * 2) ^ ((srow[i] & 7) << 4));        \
            *(short4*)(Alds + byte) = bq;                                            \
        }                                                                            \
        asm volatile("s_waitcnt lgkmcnt(0)" ::: "memory");                           \
        __builtin_amdgcn_s_barrier();                                                \
        asm volatile("" ::: "memory");                                               \
        if ((KC) + 2 < 8) {                                                          \
            _Pragma("unroll")                                                        \
            for (int i = 0; i < 4; ++i)                                              \
                CUR[i] = *(const float4*)(xp[i] + ((KC) + 2) * 64);                  \
        }                                                                            \
        _Pragma("unroll")                                                            \
        for (int ks = 0; ks < 2; ++ks) {                                             \
            bf16x8 af[4], bfw[4];                                                    \
            _Pragma("unroll")                                                        \
            for (int mf = 0; mf < 4; ++mf) {                                         \
                int row = mf * 16 + li;                                              \
                int kb = ks * 64 + lg * 16;                                          \
                af[mf] = *(const bf16x8*)(Alds + row * 128 + (kb ^ ((row & 7) << 4))); \
            }                                                                        \
            _Pragma("unroll")                                                        \
            for (int nf = 0; nf < 4; ++nf)                                           \
                bfw[nf] = *(const bf16x8*)(W1s +                                     \
                    ((size_t)((w * 4 + nf) * 16 + (KC) * 2 + ks)) * 512 + loff);     \
            _Pragma("unroll")                                                        \
            for (int mf = 0; mf < 4; ++mf)                                           \
                _Pragma("unroll")                                                    \
                for (int nf = 0; nf < 4; ++nf)                                       \
                    acc1[mf][nf] = __builtin_amdgcn_mfma_f32_16x16x32_bf16(          \
                        af[mf], bfw[nf], acc1[mf][nf], 0, 0, 0);                     \
        }                                                                            \
        asm volatile("" ::: "memory");                                               \
        __builtin_amdgcn_s_barrier();                                                \
        asm volatile("" ::: "memory");                                               \
    }

#pragma unroll
    for (int kc = 0; kc < 8; kc += 2) {
        MLP_STEP(av0, kc);
        MLP_STEP(av1, kc + 1);
    }
#undef MLP_STEP

    // T = relu(acc1 + b1) -> swizzled LDS (wave w owns cols w*64..w*64+63)
#pragma unroll
    for (int nf = 0; nf < 4; ++nf) {
        const float bv = b1[w * 64 + nf * 16 + li];
        const int col = w * 64 + nf * 16 + li;
#pragma unroll
        for (int mf = 0; mf < 4; ++mf) {
#pragma unroll
            for (int r = 0; r < 4; ++r) {
                int row = mf * 16 + lg * 4 + r;
                float tv = fmaxf(acc1[mf][nf][r] + bv, 0.f);
                int byte = row * 512 + ((col * 2) ^ ((row & 7) << 4));
                *(short*)(Tlds + byte) = f2bf(tv);
            }
        }
    }
    __syncthreads();

    // GEMM2: wave w -> rows [w*16, w*16+16), K = 256
    f32x4 acc2[4];
#pragma unroll
    for (int nf = 0; nf < 4; ++nf)
#pragma unroll
        for (int r = 0; r < 4; ++r) acc2[nf][r] = 0.f;

#pragma unroll
    for (int kt2 = 0; kt2 < 8; ++kt2) {
        int row = w * 16 + li;
        int kb = (kt2 * 32 + lg * 8) * 2;
        bf16x8 at = *(const bf16x8*)(Tlds + row * 512 + (kb ^ ((row & 7) << 4)));
#pragma unroll
        for (int nf = 0; nf < 4; ++nf) {
            bf16x8 bw = *(const bf16x8*)(W2s + ((size_t)(nf * 8 + kt2)) * 512 + loff);
            acc2[nf] = __builtin_amdgcn_mfma_f32_16x16x32_bf16(at, bw, acc2[nf], 0, 0, 0);
        }
    }

#pragma unroll
    for (int r = 0; r < 4; ++r) {
        int row = r0 + w * 16 + lg * 4 + r;
        if (row < NN) {
            const float dv = dis[row];
#pragma unroll
            for (int nf = 0; nf < 4; ++nf) {
                float hv = acc2[nf][r] + b2[nf * 16 + li];
                size_t o = (size_t)row * CLS + nf * 16 + li;
                hb[o] = __float2bfloat16(hv);
                y0[o] = __float2bfloat16(hv * dv);
            }
        }
    }
}

// ---------------- propagation: 8 lanes/edge, 8 edges per gather instr ----------------
// Plain (cached) loads on csrc/hb: they sit on the dependent critical path,
// nt hints measured -10 us/step (round 9).
__device__ __forceinline__ void acc8(float* a, u32x4 d) {
    a[0] += lobf(d.x); a[1] += hibf(d.x);
    a[2] += lobf(d.y); a[3] += hibf(d.y);
    a[4] += lobf(d.z); a[5] += hibf(d.z);
    a[6] += lobf(d.w); a[7] += hibf(d.w);
}

template <int LAST>
__global__ __launch_bounds__(256) void prop_kernel(const __hip_bfloat16* __restrict__ yin,
                                                   const __hip_bfloat16* __restrict__ hb,
                                                   const float* __restrict__ dis,
                                                   const int* __restrict__ rowptr,
                                                   const int* __restrict__ csrc,
                                                   __hip_bfloat16* __restrict__ yout,
                                                   float* __restrict__ zout) {
    const int node = blockIdx.x * 4 + (threadIdx.x >> 6);
    const int lane = threadIdx.x & 63;
    const int g = lane >> 3;
    const int ci = lane & 7;

    const u32x4* Y = (const u32x4*)yin;

    int p = __builtin_amdgcn_readfirstlane(rowptr[node]);
    const int e = __builtin_amdgcn_readfirstlane(rowptr[node + 1]);

    float a[8];
#pragma unroll
    for (int j = 0; j < 8; ++j) a[j] = 0.f;

    for (; p + 32 <= e; p += 32) {
        int s0 = csrc[p + g];
        int s1 = csrc[p + 8 + g];
        int s2 = csrc[p + 16 + g];
        int s3 = csrc[p + 24 + g];
        u32x4 d0 = Y[(size_t)s0 * 8 + ci];
        u32x4 d1 = Y[(size_t)s1 * 8 + ci];
        u32x4 d2 = Y[(size_t)s2 * 8 + ci];
        u32x4 d3 = Y[(size_t)s3 * 8 + ci];
        acc8(a, d0); acc8(a, d1); acc8(a, d2); acc8(a, d3);
    }
    for (; p + 8 <= e; p += 8) {
        int s = csrc[p + g];
        u32x4 d = Y[(size_t)s * 8 + ci];
        acc8(a, d);
    }
    if (p < e) {
        int q = p + g;
        int s = csrc[(q < e) ? q : (e - 1)];
        u32x4 d = Y[(size_t)s * 8 + ci];
        if (q < e) acc8(a, d);
    }

#pragma unroll
    for (int j = 0; j < 8; ++j) {
        a[j] += __shfl_xor(a[j], 8);
        a[j] += __shfl_xor(a[j], 16);
        a[j] += __shfl_xor(a[j], 32);
    }

    const float din = dis[node];
    u32x4 dself = Y[(size_t)node * 8 + ci];
    u32x4 dh = ((const u32x4*)hb)[(size_t)node * 8 + ci];
    float hv[8], z[8];
    acc8(a, dself);
    hv[0] = lobf(dh.x); hv[1] = hibf(dh.x);
    hv[2] = lobf(dh.y); hv[3] = hibf(dh.y);
    hv[4] = lobf(dh.z); hv[5] = hibf(dh.z);
    hv[6] = lobf(dh.w); hv[7] = hibf(dh.w);
#pragma unroll
    for (int j = 0; j < 8; ++j) z[j] = 0.9f * din * a[j] + 0.1f * hv[j];

    if (LAST) {
        float m = z[0];
#pragma unroll
        for (int j = 1; j < 8; ++j) m = fmaxf(m, z[j]);
        m = fmaxf(m, __shfl_xor(m, 1));
        m = fmaxf(m, __shfl_xor(m, 2));
        m = fmaxf(m, __shfl_xor(m, 4));
        float ss = 0.f;
#pragma unroll
        for (int j = 0; j < 8; ++j) ss += __expf(z[j] - m);
        ss += __shfl_xor(ss, 1);
        ss += __shfl_xor(ss, 2);
        ss += __shfl_xor(ss, 4);
        const float lgv = __logf(ss);
        if (g == 0) {
            f32x4 o0, o1;
            o0[0] = z[0] - m - lgv; o0[1] = z[1] - m - lgv; o0[2] = z[2] - m - lgv; o0[3] = z[3] - m - lgv;
            o1[0] = z[4] - m - lgv; o1[1] = z[5] - m - lgv; o1[2] = z[6] - m - lgv; o1[3] = z[7] - m - lgv;
            ((f32x4*)zout)[(size_t)node * 16 + ci * 2] = o0;
            ((f32x4*)zout)[(size_t)node * 16 + ci * 2 + 1] = o1;
        }
    } else {
        if (g == 0) {
            u32x4 o;
            o.x = packbf(z[0] * din, z[1] * din);
            o.y = packbf(z[2] * din, z[3] * din);
            o.z = packbf(z[4] * din, z[5] * din);
            o.w = packbf(z[6] * din, z[7] * din);
            ((u32x4*)yout)[(size_t)node * 8 + ci] = o;
        }
    }
}

extern "C" void kernel_launch(void* const* d_in, const int* in_sizes, int n_in,
                              void* d_out, int out_size, void* d_ws, size_t ws_size,
                              hipStream_t stream) {
    const float* x  = (const float*)d_in[0];
    const int*   ei = (const int*)d_in[1];
    const float* W1 = (const float*)d_in[2];
    const float* b1 = (const float*)d_in[3];
    const float* W2 = (const float*)d_in[4];
    const float* b2 = (const float*)d_in[5];
    float* out = (float*)d_out;

    const int* esrc = ei;
    const int* edst = ei + EE;

    char* w = (char*)d_ws;
    auto alloc = [&](size_t bytes) {
        char* p = w;
        w += (bytes + 255) & ~(size_t)255;
        return p;
    };
    __hip_bfloat16* hb   = (__hip_bfloat16*)alloc((size_t)NN * CLS * 2);
    __hip_bfloat16* yA   = (__hip_bfloat16*)alloc((size_t)NN * CLS * 2);
    __hip_bfloat16* yB   = (__hip_bfloat16*)alloc((size_t)NN * CLS * 2);
    __hip_bfloat16* W1Tt = (__hip_bfloat16*)alloc((size_t)HID * FIN * 2);
    __hip_bfloat16* W2Tt = (__hip_bfloat16*)alloc((size_t)CLS * HID * 2);
    float* dis    = (float*)alloc((size_t)NN * 4);
    int* rowptr   = (int*)alloc((size_t)(NN + 1) * 4);
    int* csrc     = (int*)alloc((size_t)EE * 4);
    unsigned* gbuf = (unsigned*)alloc((size_t)NBUK * BCAP * 4);
    int* gcur     = (int*)alloc(NBUK * 4);

    // CSR build (bucketed, L2-local scatter)
    zerocur_kernel<<<1, 128, 0, stream>>>(gcur);
    bucket_kernel<<<(EE + 2047) / 2048, 256, 0, stream>>>(esrc, edst, gbuf, gcur);
    csr_kernel<<<NBUK, 256, 0, stream>>>(gbuf, gcur, rowptr, dis, csrc);

    // weight prep + MLP
    w1t_kernel<<<FIN / 8, HID, 0, stream>>>(W1, W1Tt);
    w2t_kernel<<<HID / 8, CLS, 0, stream>>>(W2, W2Tt);
    mlp_kernel<<<(NN + 63) / 64, 256, 0, stream>>>(x, W1Tt, b1, W2Tt, b2, dis, hb, yA);

    // propagation
    const __hip_bfloat16* yin = yA;
    __hip_bfloat16* yout = yB;
    for (int s = 0; s < KST - 1; ++s) {
        prop_kernel<0><<<NN / 4, 256, 0, stream>>>(yin, hb, dis, rowptr, csrc, yout, nullptr);
        const __hip_bfloat16* t2 = yin;
        yin = yout;
        yout = (__hip_bfloat16*)t2;
    }
    prop_kernel<1><<<NN / 4, 256, 0, stream>>>(yin, hb, dis, rowptr, csrc, nullptr, out);
}